// Round 6
// baseline (779.733 us; speedup 1.0000x reference)
//
#include <hip/hip_runtime.h>
#include <hip/hip_bf16.h>
#include <hip/hip_cooperative_groups.h>
namespace cg = cooperative_groups;

#define N_NODES 50000
#define N_EDGES 600000
#define D 128
#define K2 256
#define SCAN_BLK 1024
#define NB_SCAN ((N_NODES + SCAN_BLK - 1) / SCAN_BLK)  // 49
#define NB_MEGA 782        // 1563 layer tiles = 2 rounds exactly; <= 1024 guaranteed resident
#define N_TILES ((N_NODES + 31) / 32)                  // 1563

typedef __bf16 bf16x8 __attribute__((ext_vector_type(8)));
typedef float  f32x16 __attribute__((ext_vector_type(16)));

__device__ __forceinline__ unsigned short f32_to_bf16_rne(float f) {
    unsigned int u = __builtin_bit_cast(unsigned int, f);
    unsigned int r = (u + 0x7fffu + ((u >> 16) & 1u)) >> 16;
    return (unsigned short)r;
}
__device__ __forceinline__ unsigned pk2(float lo, float hi) {
    return (unsigned)f32_to_bf16_rne(lo) | ((unsigned)f32_to_bf16_rne(hi) << 16);
}
__device__ __forceinline__ float bfl(unsigned int u) { return __builtin_bit_cast(float, u << 16); }
__device__ __forceinline__ float bfh(unsigned int u) { return __builtin_bit_cast(float, u & 0xffff0000u); }

// ================= phase device functions (shared by mega + fallback) =================

__device__ __forceinline__ void do_zero(int* counts, int g0, int gs) {
    for (int i = g0; i < N_NODES; i += gs) counts[i] = 0;
}

__device__ __forceinline__ void do_cvt(const float* __restrict__ x,
                                       unsigned short* __restrict__ A0, int g0, int gs) {
    for (int idx = g0; idx < N_NODES * 16; idx += gs) {
        int node = idx >> 4, g = idx & 15;
        const float4* xp = (const float4*)(x + (size_t)node * D + g * 8);
        float4 v0 = xp[0], v1 = xp[1];
        uint4 o;
        o.x = pk2(v0.x, v0.y); o.y = pk2(v0.z, v0.w);
        o.z = pk2(v1.x, v1.y); o.w = pk2(v1.z, v1.w);
        ((uint4*)A0)[(size_t)node * 16 + g] = o;
    }
}

__device__ __forceinline__ void do_prepw(const float* __restrict__ Wl1, const float* __restrict__ Wr1,
                                         const float* __restrict__ Wl2, const float* __restrict__ Wr2,
                                         unsigned short* __restrict__ WT, int g0, int gs) {
    for (int idx = g0; idx < 65536; idx += gs) {
        int layer = idx >> 15, rem = idx & 32767;
        int n = rem >> 8, k = rem & 255;
        const float* Wl = layer ? Wl2 : Wl1;
        const float* Wr = layer ? Wr2 : Wr1;
        float v = (k < D) ? Wl[k * D + n] : Wr[(k - D) * D + n];
        WT[((size_t)layer << 15) + n * K2 + k] = f32_to_bf16_rne(v);
    }
}

__device__ __forceinline__ void do_hist(const int* __restrict__ ei, int* counts, int g0, int gs) {
    for (int e = g0; e < N_EDGES; e += gs) atomicAdd(&counts[ei[N_EDGES + e]], 1);
}

__device__ __forceinline__ void do_csr(const int* __restrict__ ei, int* cursor,
                                       int* __restrict__ srcs, int g0, int gs) {
    for (int e = g0; e < N_EDGES; e += gs) {
        int src = ei[e];
        int dst = ei[N_EDGES + e];
        int pos = atomicAdd(&cursor[dst], 1);
        srcs[pos] = src;
    }
}

// per-chunk sums (call with bid < NB_SCAN; all 256 threads of the block)
__device__ __forceinline__ void do_scansum(const int* __restrict__ counts,
                                           int* __restrict__ bsum, int bid, int* wsum) {
    const int tid = threadIdx.x;
    const int lane = tid & 63, wid = tid >> 6;
    int i0 = bid * SCAN_BLK + tid * 4;
    int t = 0;
    #pragma unroll
    for (int k = 0; k < 4; ++k) if (i0 + k < N_NODES) t += counts[i0 + k];
    int acc = t;
    #pragma unroll
    for (int d = 1; d < 64; d <<= 1) {
        int v = __shfl_up(acc, d, 64);
        if (lane >= d) acc += v;
    }
    if (lane == 63) wsum[wid] = acc;
    __syncthreads();
    if (tid == 0) bsum[bid] = wsum[0] + wsum[1] + wsum[2] + wsum[3];
    __syncthreads();
}

// chunk-local exclusive scan + global prefix; writes cursor + offsets
__device__ __forceinline__ void do_scanwrite(int* __restrict__ counts,
                                             const int* __restrict__ bsum,
                                             int* __restrict__ offsets, int bid,
                                             int* wsum, int* bpre_s) {
    const int tid = threadIdx.x;
    const int lane = tid & 63, wid = tid >> 6;
    if (tid < 64) {
        int v = (tid < bid) ? bsum[tid] : 0;   // NB_SCAN=49 <= 64
        #pragma unroll
        for (int d = 32; d; d >>= 1) v += __shfl_xor(v, d, 64);
        if (tid == 0) *bpre_s = v;
    }
    int i0 = bid * SCAN_BLK + tid * 4;
    int c[4];
    int t = 0;
    #pragma unroll
    for (int k = 0; k < 4; ++k) {
        c[k] = (i0 + k < N_NODES) ? counts[i0 + k] : 0;
        t += c[k];
    }
    int acc = t;
    #pragma unroll
    for (int d = 1; d < 64; d <<= 1) {
        int v = __shfl_up(acc, d, 64);
        if (lane >= d) acc += v;
    }
    if (lane == 63) wsum[wid] = acc;
    __syncthreads();
    if (tid == 0) {
        int s = 0;
        #pragma unroll
        for (int w = 0; w < 4; ++w) { int v = wsum[w]; wsum[w] = s; s += v; }
    }
    __syncthreads();
    int excl = *bpre_s + wsum[wid] + (acc - t);
    #pragma unroll
    for (int k = 0; k < 4; ++k) {
        if (i0 + k < N_NODES) {
            counts[i0 + k] = excl;
            offsets[i0 + k + 1] = excl + c[k];
        }
        excl += c[k];
    }
    if (bid == 0 && tid == 0) offsets[0] = 0;
    __syncthreads();
}

// fused gather-mean -> LDS A-tile (MFMA fragment order) -> 4-wave MFMA GEMM
// C/D layout: col=lane&31, row=(reg&3)+8*(reg>>2)+4*(lane>>5)  [measured m74/m101]
template <bool RELU, bool OUT_BF16>
__device__ __forceinline__ void layer_phase(uint4* As4,
    const unsigned short* __restrict__ Xin, const int* __restrict__ offsets,
    const int* __restrict__ srcs, const unsigned short* __restrict__ WT,
    const float* __restrict__ bias, unsigned short* __restrict__ Hout,
    float* __restrict__ outf, int bid, int nblocks)
{
    const int tid = threadIdx.x;
    const uint4* X4 = (const uint4*)Xin;  // row = 16 uint4

    for (int tile = bid; tile < N_TILES; tile += nblocks) {
        const int base = tile * 32;
        __syncthreads();  // LDS reuse guard (prev iteration readers done)

        {   // gather: 8 threads per node, 16 features (2 uint4) each
            const int m = tid >> 3;
            const int c = tid & 7;
            const int node = base + m;
            int beg = 0, end = 0;
            if (node < N_NODES) { beg = offsets[node]; end = offsets[node + 1]; }

            float a[16];
            #pragma unroll
            for (int k = 0; k < 16; ++k) a[k] = 0.0f;

            int e = beg;
            for (; e + 1 < end; e += 2) {
                int s0 = srcs[e], s1 = srcs[e + 1];
                uint4 v0 = X4[(size_t)s0 * 16 + c * 2];
                uint4 v1 = X4[(size_t)s0 * 16 + c * 2 + 1];
                uint4 w0 = X4[(size_t)s1 * 16 + c * 2];
                uint4 w1 = X4[(size_t)s1 * 16 + c * 2 + 1];
                a[0] += bfl(v0.x); a[1] += bfh(v0.x); a[2] += bfl(v0.y); a[3] += bfh(v0.y);
                a[4] += bfl(v0.z); a[5] += bfh(v0.z); a[6] += bfl(v0.w); a[7] += bfh(v0.w);
                a[8] += bfl(v1.x); a[9] += bfh(v1.x); a[10] += bfl(v1.y); a[11] += bfh(v1.y);
                a[12] += bfl(v1.z); a[13] += bfh(v1.z); a[14] += bfl(v1.w); a[15] += bfh(v1.w);
                a[0] += bfl(w0.x); a[1] += bfh(w0.x); a[2] += bfl(w0.y); a[3] += bfh(w0.y);
                a[4] += bfl(w0.z); a[5] += bfh(w0.z); a[6] += bfl(w0.w); a[7] += bfh(w0.w);
                a[8] += bfl(w1.x); a[9] += bfh(w1.x); a[10] += bfl(w1.y); a[11] += bfh(w1.y);
                a[12] += bfl(w1.z); a[13] += bfh(w1.z); a[14] += bfl(w1.w); a[15] += bfh(w1.w);
            }
            if (e < end) {
                int s0 = srcs[e];
                uint4 v0 = X4[(size_t)s0 * 16 + c * 2];
                uint4 v1 = X4[(size_t)s0 * 16 + c * 2 + 1];
                a[0] += bfl(v0.x); a[1] += bfh(v0.x); a[2] += bfl(v0.y); a[3] += bfh(v0.y);
                a[4] += bfl(v0.z); a[5] += bfh(v0.z); a[6] += bfl(v0.w); a[7] += bfh(v0.w);
                a[8] += bfl(v1.x); a[9] += bfh(v1.x); a[10] += bfl(v1.y); a[11] += bfh(v1.y);
                a[12] += bfl(v1.z); a[13] += bfh(v1.z); a[14] += bfl(v1.w); a[15] += bfh(v1.w);
            }
            float inv = 1.0f / fmaxf((float)(end - beg), 1.0f);
            uint4 o0, o1;
            o0.x = pk2(a[0] * inv, a[1] * inv);   o0.y = pk2(a[2] * inv, a[3] * inv);
            o0.z = pk2(a[4] * inv, a[5] * inv);   o0.w = pk2(a[6] * inv, a[7] * inv);
            o1.x = pk2(a[8] * inv, a[9] * inv);   o1.y = pk2(a[10] * inv, a[11] * inv);
            o1.z = pk2(a[12] * inv, a[13] * inv); o1.w = pk2(a[14] * inv, a[15] * inv);
            As4[(c * 2 + 0) * 32 + m] = o0;       // mean half: s=c
            As4[(c * 2 + 1) * 32 + m] = o1;
            uint4 x0 = {0, 0, 0, 0}, x1 = {0, 0, 0, 0};
            if (node < N_NODES) {
                x0 = X4[(size_t)node * 16 + c * 2];
                x1 = X4[(size_t)node * 16 + c * 2 + 1];
            }
            As4[((8 + c) * 2 + 0) * 32 + m] = x0; // x half: s=8+c
            As4[((8 + c) * 2 + 1) * 32 + m] = x1;
        }
        __syncthreads();

        {   // GEMM: wave w -> cols [w*32, w*32+32), K=256
            const int l = tid & 63;
            const int w = tid >> 6;
            const int m = l & 31;
            const int kg = l >> 5;
            const int col = w * 32 + m;
            const uint4* bp = (const uint4*)(WT + (size_t)col * K2 + kg * 8);
            const bf16x8* afrag = (const bf16x8*)As4;

            f32x16 acc = {};
            #pragma unroll
            for (int s = 0; s < 16; ++s) {
                bf16x8 a = afrag[(s * 2 + kg) * 32 + m];
                bf16x8 b = __builtin_bit_cast(bf16x8, bp[s * 2]);
                acc = __builtin_amdgcn_mfma_f32_32x32x16_bf16(a, b, acc, 0, 0, 0);
            }

            const float bc = bias[col];
            const int halfadd = kg * 4;
            #pragma unroll
            for (int r = 0; r < 16; ++r) {
                int rw = base + (r & 3) + 8 * (r >> 2) + halfadd;
                if (rw < N_NODES) {
                    float v = acc[r] + bc;
                    if (RELU) v = fmaxf(v, 0.0f);
                    if (OUT_BF16) Hout[(size_t)rw * D + col] = f32_to_bf16_rne(v);
                    else outf[(size_t)rw * D + col] = v;
                }
            }
        }
    }
}

// ================= mega (cooperative, 1 dispatch) =================
__global__ __launch_bounds__(256, 4) void mega_kernel(
    const float* __restrict__ x, const int* __restrict__ ei,
    const float* __restrict__ Wl1, const float* __restrict__ Wr1, const float* __restrict__ b1,
    const float* __restrict__ Wl2, const float* __restrict__ Wr2, const float* __restrict__ b2,
    unsigned short* A0, unsigned short* A1, unsigned short* WT,
    int* counts, int* offsets, int* srcs, int* bsum, float* out)
{
    cg::grid_group grid = cg::this_grid();
    __shared__ uint4 As4[16 * 2 * 32];
    __shared__ int wsum[4];
    __shared__ int bpre_s;

    const int bid = blockIdx.x;
    const int g0 = bid * 256 + threadIdx.x;
    const int gs = gridDim.x * 256;

    // phase 0: zero counts | x->bf16 | W->WT
    do_zero(counts, g0, gs);
    do_cvt(x, A0, g0, gs);
    do_prepw(Wl1, Wr1, Wl2, Wr2, WT, g0, gs);
    grid.sync();

    // phase 1: histogram
    do_hist(ei, counts, g0, gs);
    grid.sync();

    // phase 2: chunk sums
    if (bid < NB_SCAN) do_scansum(counts, bsum, bid, wsum);
    grid.sync();

    // phase 3: prefix + cursor/offset write
    if (bid < NB_SCAN) do_scanwrite(counts, bsum, offsets, bid, wsum, &bpre_s);
    grid.sync();

    // phase 4: CSR scatter
    do_csr(ei, counts, srcs, g0, gs);
    grid.sync();

    // phase 5: layer 1 (A0 -> h bf16 in A1)
    layer_phase<true, true>(As4, A0, offsets, srcs, WT, b1, A1, nullptr, bid, gridDim.x);
    grid.sync();

    // phase 6: layer 2 (A1 -> f32 out)
    layer_phase<false, false>(As4, A1, offsets, srcs, WT + (size_t)D * K2, b2, nullptr, out, bid, gridDim.x);
}

// ================= discrete fallback kernels =================
__global__ __launch_bounds__(256) void prep_kernel(
    const float* __restrict__ x,
    const float* __restrict__ Wl1, const float* __restrict__ Wr1,
    const float* __restrict__ Wl2, const float* __restrict__ Wr2,
    unsigned short* A0, unsigned short* WT, int* counts) {
    const int g0 = blockIdx.x * 256 + threadIdx.x;
    const int gs = gridDim.x * 256;
    do_zero(counts, g0, gs);
    do_cvt(x, A0, g0, gs);
    do_prepw(Wl1, Wr1, Wl2, Wr2, WT, g0, gs);
}
__global__ __launch_bounds__(256) void hist_kernel(const int* __restrict__ ei, int* counts) {
    do_hist(ei, counts, blockIdx.x * 256 + threadIdx.x, gridDim.x * 256);
}
__global__ __launch_bounds__(256) void scan_s1(const int* __restrict__ counts, int* bsum) {
    __shared__ int wsum[4];
    do_scansum(counts, bsum, blockIdx.x, wsum);
}
__global__ __launch_bounds__(256) void scan_s3(int* counts, const int* bsum, int* offsets) {
    __shared__ int wsum[4];
    __shared__ int bpre_s;
    do_scanwrite(counts, bsum, offsets, blockIdx.x, wsum, &bpre_s);
}
__global__ __launch_bounds__(256) void csr_kernel(const int* __restrict__ ei, int* cursor, int* srcs) {
    do_csr(ei, cursor, srcs, blockIdx.x * 256 + threadIdx.x, gridDim.x * 256);
}
template <bool RELU, bool OUT_BF16>
__global__ __launch_bounds__(256) void layer_kernel(
    const unsigned short* __restrict__ Xin, const int* __restrict__ offsets,
    const int* __restrict__ srcs, const unsigned short* __restrict__ WT,
    const float* __restrict__ bias, unsigned short* Hout, float* outf) {
    __shared__ uint4 As4[16 * 2 * 32];
    layer_phase<RELU, OUT_BF16>(As4, Xin, offsets, srcs, WT, bias, Hout, outf,
                                blockIdx.x, gridDim.x);
}

extern "C" void kernel_launch(void* const* d_in, const int* in_sizes, int n_in,
                              void* d_out, int out_size, void* d_ws, size_t ws_size,
                              hipStream_t stream) {
    const float* x   = (const float*)d_in[0];
    const int*   ei  = (const int*)d_in[1];
    const float* Wl1 = (const float*)d_in[2];
    const float* Wr1 = (const float*)d_in[3];
    const float* b1  = (const float*)d_in[4];
    const float* Wl2 = (const float*)d_in[5];
    const float* Wr2 = (const float*)d_in[6];
    const float* b2  = (const float*)d_in[7];
    float* out = (float*)d_out;

    unsigned short* A0 = (unsigned short*)d_ws;
    unsigned short* A1 = A0 + (size_t)N_NODES * D;
    unsigned short* WT = A1 + (size_t)N_NODES * D;
    int* counts  = (int*)(WT + 2 * D * K2);
    int* offsets = counts + N_NODES;
    int* srcs    = offsets + N_NODES + 1;
    int* bsum    = srcs + N_EDGES;

    void* args[] = {(void*)&x, (void*)&ei, (void*)&Wl1, (void*)&Wr1, (void*)&b1,
                    (void*)&Wl2, (void*)&Wr2, (void*)&b2,
                    (void*)&A0, (void*)&A1, (void*)&WT,
                    (void*)&counts, (void*)&offsets, (void*)&srcs, (void*)&bsum, (void*)&out};
    hipError_t err = hipLaunchCooperativeKernel((void*)mega_kernel, dim3(NB_MEGA), dim3(256),
                                                args, 0, stream);
    if (err != hipSuccess) {
        // discrete fallback (identical numerics)
        prep_kernel<<<1024, 256, 0, stream>>>(x, Wl1, Wr1, Wl2, Wr2, A0, WT, counts);
        hist_kernel<<<1024, 256, 0, stream>>>(ei, counts);
        scan_s1<<<NB_SCAN, 256, 0, stream>>>(counts, bsum);
        scan_s3<<<NB_SCAN, 256, 0, stream>>>(counts, bsum, offsets);
        csr_kernel<<<1024, 256, 0, stream>>>(ei, counts, srcs);
        layer_kernel<true, true><<<N_TILES, 256, 0, stream>>>(A0, offsets, srcs, WT, b1, A1, nullptr);
        layer_kernel<false, false><<<N_TILES, 256, 0, stream>>>(A1, offsets, srcs,
                                                                WT + (size_t)D * K2, b2, nullptr, out);
    }
}

// Round 7
// 240.505 us; speedup vs baseline: 3.2421x; 3.2421x over previous
//
#include <hip/hip_runtime.h>
#include <hip/hip_bf16.h>

#define N_NODES 50000
#define N_EDGES 600000
#define D 128
#define K2 256  // 2*D
#define SCAN_BLK 1024
#define NB_SCAN ((N_NODES + SCAN_BLK - 1) / SCAN_BLK)  // 49

// fused-prep block ranges
#define CVT_BLOCKS  (N_NODES * 16 / 256)                 // 3125
#define HIST_BLOCKS ((N_EDGES + 255) / 256)              // 2344
#define PREPW_BLOCKS (2 * D * K2 / 256)                  // 256
#define PREP_GRID (CVT_BLOCKS + HIST_BLOCKS + PREPW_BLOCKS)

#define AS_STRIDE 33   // uint4 stride pad: kills the 8-way LDS write conflict (banks step 8/c)

typedef __bf16 bf16x8 __attribute__((ext_vector_type(8)));
typedef float  f32x16 __attribute__((ext_vector_type(16)));

__device__ __forceinline__ unsigned short f32_to_bf16_rne(float f) {
    unsigned int u = __builtin_bit_cast(unsigned int, f);
    unsigned int r = (u + 0x7fffu + ((u >> 16) & 1u)) >> 16;
    return (unsigned short)r;
}
__device__ __forceinline__ unsigned pk2(float lo, float hi) {
    return (unsigned)f32_to_bf16_rne(lo) | ((unsigned)f32_to_bf16_rne(hi) << 16);
}
__device__ __forceinline__ float bfl(unsigned int u) { return __builtin_bit_cast(float, u << 16); }
__device__ __forceinline__ float bfh(unsigned int u) { return __builtin_bit_cast(float, u & 0xffff0000u); }

__device__ __forceinline__ void acc16(float* a, uint4 v0, uint4 v1) {
    a[0] += bfl(v0.x); a[1] += bfh(v0.x); a[2] += bfl(v0.y); a[3] += bfh(v0.y);
    a[4] += bfl(v0.z); a[5] += bfh(v0.z); a[6] += bfl(v0.w); a[7] += bfh(v0.w);
    a[8] += bfl(v1.x); a[9] += bfh(v1.x); a[10] += bfl(v1.y); a[11] += bfh(v1.y);
    a[12] += bfl(v1.z); a[13] += bfh(v1.z); a[14] += bfl(v1.w); a[15] += bfh(v1.w);
}

// ---------- fused prep: x->bf16 A0 | edge histogram | W->WT bf16 ----------
__global__ __launch_bounds__(256) void prep_kernel(
    const float* __restrict__ x, const int* __restrict__ ei,
    const float* __restrict__ Wl1, const float* __restrict__ Wr1,
    const float* __restrict__ Wl2, const float* __restrict__ Wr2,
    unsigned short* __restrict__ A0, unsigned short* __restrict__ WT,
    int* __restrict__ counts)
{
    const int b = blockIdx.x;
    if (b < CVT_BLOCKS) {
        int idx = b * 256 + threadIdx.x;       // 800000 exactly
        int node = idx >> 4, g = idx & 15;
        const float4* xp = (const float4*)(x + (size_t)node * D + g * 8);
        float4 v0 = xp[0], v1 = xp[1];
        uint4 o;
        o.x = pk2(v0.x, v0.y); o.y = pk2(v0.z, v0.w);
        o.z = pk2(v1.x, v1.y); o.w = pk2(v1.z, v1.w);
        ((uint4*)A0)[(size_t)node * 16 + g] = o;
    } else if (b < CVT_BLOCKS + HIST_BLOCKS) {
        int e = (b - CVT_BLOCKS) * 256 + threadIdx.x;
        if (e < N_EDGES) atomicAdd(&counts[ei[N_EDGES + e]], 1);
    } else {
        // WT[layer][n][k]: k<128 -> Wl[k][n], k>=128 -> Wr[k-128][n]
        int idx = (b - CVT_BLOCKS - HIST_BLOCKS) * 256 + threadIdx.x;  // 65536 exactly
        int layer = idx >> 15, rem = idx & 32767;
        int n = rem >> 8, k = rem & 255;
        const float* Wl = layer ? Wl2 : Wl1;
        const float* Wr = layer ? Wr2 : Wr1;
        float v = (k < D) ? Wl[k * D + n] : Wr[(k - D) * D + n];
        WT[((size_t)layer << 15) + n * K2 + k] = f32_to_bf16_rne(v);
    }
}

// ---- scan phase 1: per-block sums (256 thr x 4 elems) ----
__global__ __launch_bounds__(256) void scan_p1(const int* __restrict__ counts,
                                               int* __restrict__ bsum) {
    __shared__ int wsum[4];
    const int tid = threadIdx.x;
    const int lane = tid & 63, wid = tid >> 6;
    int i0 = blockIdx.x * SCAN_BLK + tid * 4;
    int t = 0;
    #pragma unroll
    for (int k = 0; k < 4; ++k) if (i0 + k < N_NODES) t += counts[i0 + k];
    int acc = t;
    #pragma unroll
    for (int d = 1; d < 64; d <<= 1) {
        int v = __shfl_up(acc, d, 64);
        if (lane >= d) acc += v;
    }
    if (lane == 63) wsum[wid] = acc;
    __syncthreads();
    if (tid == 0) bsum[blockIdx.x] = wsum[0] + wsum[1] + wsum[2] + wsum[3];
}

// ---- scan phase 2+3 fused: each block sums its predecessors' bsums itself ----
__global__ __launch_bounds__(256) void scan_p3(int* __restrict__ counts,
                                               const int* __restrict__ bsum,
                                               int* __restrict__ offsets) {
    __shared__ int wsum[4];
    __shared__ int bpre_s;
    const int tid = threadIdx.x;
    const int lane = tid & 63, wid = tid >> 6;
    if (tid < 64) {
        int v = (tid < blockIdx.x) ? bsum[tid] : 0;   // NB_SCAN=49 <= 64
        #pragma unroll
        for (int d = 32; d; d >>= 1) v += __shfl_xor(v, d, 64);
        if (tid == 0) bpre_s = v;
    }
    int i0 = blockIdx.x * SCAN_BLK + tid * 4;
    int c[4];
    int t = 0;
    #pragma unroll
    for (int k = 0; k < 4; ++k) {
        c[k] = (i0 + k < N_NODES) ? counts[i0 + k] : 0;
        t += c[k];
    }
    int acc = t;
    #pragma unroll
    for (int d = 1; d < 64; d <<= 1) {
        int v = __shfl_up(acc, d, 64);
        if (lane >= d) acc += v;
    }
    if (lane == 63) wsum[wid] = acc;
    __syncthreads();
    if (tid == 0) {
        int s = 0;
        #pragma unroll
        for (int w = 0; w < 4; ++w) { int v = wsum[w]; wsum[w] = s; s += v; }
    }
    __syncthreads();
    int excl = bpre_s + wsum[wid] + (acc - t);
    #pragma unroll
    for (int k = 0; k < 4; ++k) {
        if (i0 + k < N_NODES) {
            counts[i0 + k] = excl;              // scatter cursor
            offsets[i0 + k + 1] = excl + c[k];  // segment end
        }
        excl += c[k];
    }
    if (blockIdx.x == 0 && tid == 0) offsets[0] = 0;
}

__global__ __launch_bounds__(256) void build_csr_kernel(const int* __restrict__ ei,
                                                        int* __restrict__ cursor,
                                                        int* __restrict__ sorted_src) {
    int e = blockIdx.x * blockDim.x + threadIdx.x;
    if (e < N_EDGES) {
        int src = ei[e];
        int dst = ei[N_EDGES + e];
        int pos = atomicAdd(&cursor[dst], 1);
        sorted_src[pos] = src;
    }
}

// ---------- fused layer: gather-mean -> LDS A-tile (fragment order) -> MFMA ----------
// Block = 256 thr, 32 nodes. As4[(s*2+kg)*AS_STRIDE + m] holds A[m][k], k=s*16+kg*8+j.
// Mean half s=0..7, self-x half s=8..15. GEMM: wave w -> cols [w*32,w*32+32), K=256.
// C/D: col=lane&31, row=(reg&3)+8*(reg>>2)+4*(lane>>5)  [measured m74/m101].
template <bool RELU, bool OUT_BF16>
__global__ __launch_bounds__(256) void layer_kernel(
    const unsigned short* __restrict__ Xin,   // [N][128] bf16
    const int* __restrict__ offsets, const int* __restrict__ srcs,
    const unsigned short* __restrict__ WT,    // [128][256] bf16
    const float* __restrict__ bias,
    unsigned short* __restrict__ Hout,        // layer1: h bf16 [N][128]
    float* __restrict__ outf)                 // layer2: f32 [N][128]
{
    __shared__ uint4 As4[16 * 2 * AS_STRIDE];  // 16.9 KB
    const int tid = threadIdx.x;
    const int base = blockIdx.x * 32;
    const uint4* X4 = (const uint4*)Xin;       // row stride = 16 uint4

    // ---- gather phase: 8 threads per node, unroll x4 edges (8 loads in flight) ----
    {
        const int m = tid >> 3;
        const int c = tid & 7;
        const int node = base + m;
        int beg = 0, end = 0;
        if (node < N_NODES) { beg = offsets[node]; end = offsets[node + 1]; }

        float a[16];
        #pragma unroll
        for (int k = 0; k < 16; ++k) a[k] = 0.0f;

        int e = beg;
        for (; e + 3 < end; e += 4) {
            int s0 = srcs[e], s1 = srcs[e + 1], s2 = srcs[e + 2], s3 = srcs[e + 3];
            uint4 v0 = X4[(size_t)s0 * 16 + c * 2];
            uint4 v1 = X4[(size_t)s0 * 16 + c * 2 + 1];
            uint4 w0 = X4[(size_t)s1 * 16 + c * 2];
            uint4 w1 = X4[(size_t)s1 * 16 + c * 2 + 1];
            uint4 y0 = X4[(size_t)s2 * 16 + c * 2];
            uint4 y1 = X4[(size_t)s2 * 16 + c * 2 + 1];
            uint4 z0 = X4[(size_t)s3 * 16 + c * 2];
            uint4 z1 = X4[(size_t)s3 * 16 + c * 2 + 1];
            acc16(a, v0, v1); acc16(a, w0, w1); acc16(a, y0, y1); acc16(a, z0, z1);
        }
        for (; e < end; ++e) {
            int s0 = srcs[e];
            uint4 v0 = X4[(size_t)s0 * 16 + c * 2];
            uint4 v1 = X4[(size_t)s0 * 16 + c * 2 + 1];
            acc16(a, v0, v1);
        }
        float inv = 1.0f / fmaxf((float)(end - beg), 1.0f);
        uint4 o0, o1;
        o0.x = pk2(a[0] * inv, a[1] * inv);   o0.y = pk2(a[2] * inv, a[3] * inv);
        o0.z = pk2(a[4] * inv, a[5] * inv);   o0.w = pk2(a[6] * inv, a[7] * inv);
        o1.x = pk2(a[8] * inv, a[9] * inv);   o1.y = pk2(a[10] * inv, a[11] * inv);
        o1.z = pk2(a[12] * inv, a[13] * inv); o1.w = pk2(a[14] * inv, a[15] * inv);
        As4[(c * 2 + 0) * AS_STRIDE + m] = o0;        // mean half: s=c
        As4[(c * 2 + 1) * AS_STRIDE + m] = o1;
        uint4 x0 = {0, 0, 0, 0}, x1 = {0, 0, 0, 0};
        if (node < N_NODES) {
            x0 = X4[(size_t)node * 16 + c * 2];
            x1 = X4[(size_t)node * 16 + c * 2 + 1];
        }
        As4[((8 + c) * 2 + 0) * AS_STRIDE + m] = x0;  // x half: s=8+c
        As4[((8 + c) * 2 + 1) * AS_STRIDE + m] = x1;
    }
    __syncthreads();

    // ---- GEMM phase ----
    const int l = tid & 63;
    const int w = tid >> 6;
    const int m = l & 31;
    const int kg = l >> 5;
    const int col = w * 32 + m;
    const uint4* bp = (const uint4*)(WT + (size_t)col * K2 + kg * 8);
    const bf16x8* afrag = (const bf16x8*)As4;

    f32x16 acc = {};
    #pragma unroll
    for (int s = 0; s < 16; ++s) {
        bf16x8 a = afrag[(s * 2 + kg) * AS_STRIDE + m];
        bf16x8 b = __builtin_bit_cast(bf16x8, bp[s * 2]);
        acc = __builtin_amdgcn_mfma_f32_32x32x16_bf16(a, b, acc, 0, 0, 0);
    }

    const float bc = bias[col];
    const int halfadd = kg * 4;
    #pragma unroll
    for (int r = 0; r < 16; ++r) {
        int rw = base + (r & 3) + 8 * (r >> 2) + halfadd;
        if (rw < N_NODES) {
            float v = acc[r] + bc;
            if (RELU) v = fmaxf(v, 0.0f);
            if (OUT_BF16) Hout[(size_t)rw * D + col] = f32_to_bf16_rne(v);
            else outf[(size_t)rw * D + col] = v;
        }
    }
}

extern "C" void kernel_launch(void* const* d_in, const int* in_sizes, int n_in,
                              void* d_out, int out_size, void* d_ws, size_t ws_size,
                              hipStream_t stream) {
    const float* x   = (const float*)d_in[0];
    const int*   ei  = (const int*)d_in[1];
    const float* Wl1 = (const float*)d_in[2];
    const float* Wr1 = (const float*)d_in[3];
    const float* b1  = (const float*)d_in[4];
    const float* Wl2 = (const float*)d_in[5];
    const float* Wr2 = (const float*)d_in[6];
    const float* b2  = (const float*)d_in[7];
    float* out = (float*)d_out;

    // ws: A0 [N][128] bf16 | A1 [N][128] bf16 | WT [2][128][256] bf16 |
    //     counts [N] | offsets [N+1] | srcs [E] | bsum [64]
    unsigned short* A0 = (unsigned short*)d_ws;
    unsigned short* A1 = A0 + (size_t)N_NODES * D;
    unsigned short* WT = A1 + (size_t)N_NODES * D;
    int* counts  = (int*)(WT + 2 * D * K2);
    int* offsets = counts + N_NODES;
    int* srcs    = offsets + N_NODES + 1;
    int* bsum    = srcs + N_EDGES;

    const int layerBlocks = (N_NODES + 31) / 32;  // 1563

    hipMemsetAsync(counts, 0, N_NODES * sizeof(int), stream);
    prep_kernel<<<PREP_GRID, 256, 0, stream>>>(x, ei, Wl1, Wr1, Wl2, Wr2, A0, WT, counts);
    scan_p1<<<NB_SCAN, 256, 0, stream>>>(counts, bsum);
    scan_p3<<<NB_SCAN, 256, 0, stream>>>(counts, bsum, offsets);
    build_csr_kernel<<<HIST_BLOCKS, 256, 0, stream>>>(ei, counts, srcs);

    layer_kernel<true, true><<<layerBlocks, 256, 0, stream>>>(
        A0, offsets, srcs, WT, b1, A1, nullptr);
    layer_kernel<false, false><<<layerBlocks, 256, 0, stream>>>(
        A1, offsets, srcs, WT + (size_t)D * K2, b2, nullptr, out);
}

// Round 8
// 226.899 us; speedup vs baseline: 3.4365x; 1.0600x over previous
//
#include <hip/hip_runtime.h>
#include <hip/hip_bf16.h>

#define N_NODES 50000
#define N_EDGES 600000
#define D 128
#define K2 256  // 2*D
#define SCAN_BLK 1024
#define NB_SCAN ((N_NODES + SCAN_BLK - 1) / SCAN_BLK)  // 49

// fused-prep block ranges
#define CVT_BLOCKS  (N_NODES * 16 / 256)                 // 3125
#define HIST_BLOCKS ((N_EDGES + 255) / 256)              // 2344
#define PREPW_BLOCKS (2 * D * K2 / 256)                  // 256
#define PREP_GRID (CVT_BLOCKS + HIST_BLOCKS + PREPW_BLOCKS)

#define AS_STRIDE 33   // uint4 stride pad: LDS write aliasing <=2-way (free per m136)

typedef __bf16 bf16x8 __attribute__((ext_vector_type(8)));
typedef float  f32x16 __attribute__((ext_vector_type(16)));

__device__ __forceinline__ unsigned short f32_to_bf16_rne(float f) {
    unsigned int u = __builtin_bit_cast(unsigned int, f);
    unsigned int r = (u + 0x7fffu + ((u >> 16) & 1u)) >> 16;
    return (unsigned short)r;
}
__device__ __forceinline__ unsigned pk2(float lo, float hi) {
    return (unsigned)f32_to_bf16_rne(lo) | ((unsigned)f32_to_bf16_rne(hi) << 16);
}
__device__ __forceinline__ float bfl(unsigned int u) { return __builtin_bit_cast(float, u << 16); }
__device__ __forceinline__ float bfh(unsigned int u) { return __builtin_bit_cast(float, u & 0xffff0000u); }

__device__ __forceinline__ void acc8(float* a, uint4 v) {
    a[0] += bfl(v.x); a[1] += bfh(v.x); a[2] += bfl(v.y); a[3] += bfh(v.y);
    a[4] += bfl(v.z); a[5] += bfh(v.z); a[6] += bfl(v.w); a[7] += bfh(v.w);
}

// ---------- fused prep: x->bf16 A0 | edge histogram | W->WT bf16 ----------
__global__ __launch_bounds__(256) void prep_kernel(
    const float* __restrict__ x, const int* __restrict__ ei,
    const float* __restrict__ Wl1, const float* __restrict__ Wr1,
    const float* __restrict__ Wl2, const float* __restrict__ Wr2,
    unsigned short* __restrict__ A0, unsigned short* __restrict__ WT,
    int* __restrict__ counts)
{
    const int b = blockIdx.x;
    if (b < CVT_BLOCKS) {
        int idx = b * 256 + threadIdx.x;       // 800000 exactly
        int node = idx >> 4, g = idx & 15;
        const float4* xp = (const float4*)(x + (size_t)node * D + g * 8);
        float4 v0 = xp[0], v1 = xp[1];
        uint4 o;
        o.x = pk2(v0.x, v0.y); o.y = pk2(v0.z, v0.w);
        o.z = pk2(v1.x, v1.y); o.w = pk2(v1.z, v1.w);
        ((uint4*)A0)[(size_t)node * 16 + g] = o;
    } else if (b < CVT_BLOCKS + HIST_BLOCKS) {
        int e = (b - CVT_BLOCKS) * 256 + threadIdx.x;
        if (e < N_EDGES) atomicAdd(&counts[ei[N_EDGES + e]], 1);
    } else {
        // WT[layer][n][k]: k<128 -> Wl[k][n], k>=128 -> Wr[k-128][n]
        int idx = (b - CVT_BLOCKS - HIST_BLOCKS) * 256 + threadIdx.x;  // 65536 exactly
        int layer = idx >> 15, rem = idx & 32767;
        int n = rem >> 8, k = rem & 255;
        const float* Wl = layer ? Wl2 : Wl1;
        const float* Wr = layer ? Wr2 : Wr1;
        float v = (k < D) ? Wl[k * D + n] : Wr[(k - D) * D + n];
        WT[((size_t)layer << 15) + n * K2 + k] = f32_to_bf16_rne(v);
    }
}

// ---- scan phase 1: per-block sums (256 thr x 4 elems) ----
__global__ __launch_bounds__(256) void scan_p1(const int* __restrict__ counts,
                                               int* __restrict__ bsum) {
    __shared__ int wsum[4];
    const int tid = threadIdx.x;
    const int lane = tid & 63, wid = tid >> 6;
    int i0 = blockIdx.x * SCAN_BLK + tid * 4;
    int t = 0;
    #pragma unroll
    for (int k = 0; k < 4; ++k) if (i0 + k < N_NODES) t += counts[i0 + k];
    int acc = t;
    #pragma unroll
    for (int d = 1; d < 64; d <<= 1) {
        int v = __shfl_up(acc, d, 64);
        if (lane >= d) acc += v;
    }
    if (lane == 63) wsum[wid] = acc;
    __syncthreads();
    if (tid == 0) bsum[blockIdx.x] = wsum[0] + wsum[1] + wsum[2] + wsum[3];
}

// ---- scan phase 2+3 fused: each block sums its predecessors' bsums itself ----
__global__ __launch_bounds__(256) void scan_p3(int* __restrict__ counts,
                                               const int* __restrict__ bsum,
                                               int* __restrict__ offsets) {
    __shared__ int wsum[4];
    __shared__ int bpre_s;
    const int tid = threadIdx.x;
    const int lane = tid & 63, wid = tid >> 6;
    if (tid < 64) {
        int v = (tid < blockIdx.x) ? bsum[tid] : 0;   // NB_SCAN=49 <= 64
        #pragma unroll
        for (int d = 32; d; d >>= 1) v += __shfl_xor(v, d, 64);
        if (tid == 0) bpre_s = v;
    }
    int i0 = blockIdx.x * SCAN_BLK + tid * 4;
    int c[4];
    int t = 0;
    #pragma unroll
    for (int k = 0; k < 4; ++k) {
        c[k] = (i0 + k < N_NODES) ? counts[i0 + k] : 0;
        t += c[k];
    }
    int acc = t;
    #pragma unroll
    for (int d = 1; d < 64; d <<= 1) {
        int v = __shfl_up(acc, d, 64);
        if (lane >= d) acc += v;
    }
    if (lane == 63) wsum[wid] = acc;
    __syncthreads();
    if (tid == 0) {
        int s = 0;
        #pragma unroll
        for (int w = 0; w < 4; ++w) { int v = wsum[w]; wsum[w] = s; s += v; }
    }
    __syncthreads();
    int excl = bpre_s + wsum[wid] + (acc - t);
    #pragma unroll
    for (int k = 0; k < 4; ++k) {
        if (i0 + k < N_NODES) {
            counts[i0 + k] = excl;              // scatter cursor
            offsets[i0 + k + 1] = excl + c[k];  // segment end
        }
        excl += c[k];
    }
    if (blockIdx.x == 0 && tid == 0) offsets[0] = 0;
}

__global__ __launch_bounds__(256) void build_csr_kernel(const int* __restrict__ ei,
                                                        int* __restrict__ cursor,
                                                        int* __restrict__ sorted_src) {
    int e = blockIdx.x * blockDim.x + threadIdx.x;
    if (e < N_EDGES) {
        int src = ei[e];
        int dst = ei[N_EDGES + e];
        int pos = atomicAdd(&cursor[dst], 1);
        sorted_src[pos] = src;
    }
}

// ---------- fused layer: gather-mean -> LDS A-tile (fragment order) -> MFMA ----------
// Block = 256 thr, 32 nodes. As4[slot*AS_STRIDE + m] holds A[m][slot*8 .. slot*8+7]:
// slots 0..15 = mean half (k<128), 16..31 = self-x half. Gather: 16 lanes/node,
// ONE uint4 per lane per edge => each edge = one fully-coalesced 256 B read.
// GEMM: wave w -> cols [w*32,w*32+32), K=256.
// C/D: col=lane&31, row=(reg&3)+8*(reg>>2)+4*(lane>>5)  [measured m74/m101].
template <bool RELU, bool OUT_BF16>
__global__ __launch_bounds__(256) void layer_kernel(
    const unsigned short* __restrict__ Xin,   // [N][128] bf16
    const int* __restrict__ offsets, const int* __restrict__ srcs,
    const unsigned short* __restrict__ WT,    // [128][256] bf16
    const float* __restrict__ bias,
    unsigned short* __restrict__ Hout,        // layer1: h bf16 [N][128]
    float* __restrict__ outf)                 // layer2: f32 [N][128]
{
    __shared__ uint4 As4[32 * AS_STRIDE];      // 16.9 KB
    const int tid = threadIdx.x;
    const int base = blockIdx.x * 32;
    const uint4* X4 = (const uint4*)Xin;       // row stride = 16 uint4

    // ---- gather phase: 16 lanes per node, 2 nodes per thread ----
    {
        const int c  = tid & 15;               // 16B chunk within row
        const int m0 = tid >> 4;               // 0..15
        #pragma unroll
        for (int half = 0; half < 2; ++half) {
            const int m = m0 + half * 16;
            const int node = base + m;
            int beg = 0, end = 0;
            if (node < N_NODES) { beg = offsets[node]; end = offsets[node + 1]; }

            float a[8];
            #pragma unroll
            for (int k = 0; k < 8; ++k) a[k] = 0.0f;

            int e = beg;
            for (; e + 3 < end; e += 4) {
                int s0 = srcs[e], s1 = srcs[e + 1], s2 = srcs[e + 2], s3 = srcs[e + 3];
                uint4 v0 = X4[(size_t)s0 * 16 + c];
                uint4 v1 = X4[(size_t)s1 * 16 + c];
                uint4 v2 = X4[(size_t)s2 * 16 + c];
                uint4 v3 = X4[(size_t)s3 * 16 + c];
                acc8(a, v0); acc8(a, v1); acc8(a, v2); acc8(a, v3);
            }
            for (; e < end; ++e) acc8(a, X4[(size_t)srcs[e] * 16 + c]);

            float inv = 1.0f / fmaxf((float)(end - beg), 1.0f);
            uint4 o;
            o.x = pk2(a[0] * inv, a[1] * inv); o.y = pk2(a[2] * inv, a[3] * inv);
            o.z = pk2(a[4] * inv, a[5] * inv); o.w = pk2(a[6] * inv, a[7] * inv);
            As4[c * AS_STRIDE + m] = o;                    // mean half: slot c
            uint4 xv = {0, 0, 0, 0};
            if (node < N_NODES) xv = X4[(size_t)node * 16 + c];
            As4[(16 + c) * AS_STRIDE + m] = xv;            // x half: slot 16+c
        }
    }
    __syncthreads();

    // ---- GEMM phase ----
    const int l = tid & 63;
    const int w = tid >> 6;
    const int m = l & 31;
    const int kg = l >> 5;
    const int col = w * 32 + m;
    const uint4* bp = (const uint4*)(WT + (size_t)col * K2 + kg * 8);
    const bf16x8* afrag = (const bf16x8*)As4;

    f32x16 acc = {};
    #pragma unroll
    for (int s = 0; s < 16; ++s) {
        bf16x8 a = afrag[(s * 2 + kg) * AS_STRIDE + m];
        bf16x8 b = __builtin_bit_cast(bf16x8, bp[s * 2]);
        acc = __builtin_amdgcn_mfma_f32_32x32x16_bf16(a, b, acc, 0, 0, 0);
    }

    const float bc = bias[col];
    const int halfadd = kg * 4;
    #pragma unroll
    for (int r = 0; r < 16; ++r) {
        int rw = base + (r & 3) + 8 * (r >> 2) + halfadd;
        if (rw < N_NODES) {
            float v = acc[r] + bc;
            if (RELU) v = fmaxf(v, 0.0f);
            if (OUT_BF16) Hout[(size_t)rw * D + col] = f32_to_bf16_rne(v);
            else outf[(size_t)rw * D + col] = v;
        }
    }
}

extern "C" void kernel_launch(void* const* d_in, const int* in_sizes, int n_in,
                              void* d_out, int out_size, void* d_ws, size_t ws_size,
                              hipStream_t stream) {
    const float* x   = (const float*)d_in[0];
    const int*   ei  = (const int*)d_in[1];
    const float* Wl1 = (const float*)d_in[2];
    const float* Wr1 = (const float*)d_in[3];
    const float* b1  = (const float*)d_in[4];
    const float* Wl2 = (const float*)d_in[5];
    const float* Wr2 = (const float*)d_in[6];
    const float* b2  = (const float*)d_in[7];
    float* out = (float*)d_out;

    // ws: A0 [N][128] bf16 | A1 [N][128] bf16 | WT [2][128][256] bf16 |
    //     counts [N] | offsets [N+1] | srcs [E] | bsum [64]
    unsigned short* A0 = (unsigned short*)d_ws;
    unsigned short* A1 = A0 + (size_t)N_NODES * D;
    unsigned short* WT = A1 + (size_t)N_NODES * D;
    int* counts  = (int*)(WT + 2 * D * K2);
    int* offsets = counts + N_NODES;
    int* srcs    = offsets + N_NODES + 1;
    int* bsum    = srcs + N_EDGES;

    const int layerBlocks = (N_NODES + 31) / 32;  // 1563

    hipMemsetAsync(counts, 0, N_NODES * sizeof(int), stream);
    prep_kernel<<<PREP_GRID, 256, 0, stream>>>(x, ei, Wl1, Wr1, Wl2, Wr2, A0, WT, counts);
    scan_p1<<<NB_SCAN, 256, 0, stream>>>(counts, bsum);
    scan_p3<<<NB_SCAN, 256, 0, stream>>>(counts, bsum, offsets);
    build_csr_kernel<<<HIST_BLOCKS, 256, 0, stream>>>(ei, counts, srcs);

    layer_kernel<true, true><<<layerBlocks, 256, 0, stream>>>(
        A0, offsets, srcs, WT, b1, A1, nullptr);
    layer_kernel<false, false><<<layerBlocks, 256, 0, stream>>>(
        A1, offsets, srcs, WT + (size_t)D * K2, b2, nullptr, out);
}